// Round 1
// baseline (220.431 us; speedup 1.0000x reference)
//
#include <hip/hip_runtime.h>
#include <hip/hip_bf16.h>
#include <stdint.h>
#include <stddef.h>

typedef __attribute__((ext_vector_type(4))) float f32x4;
typedef __attribute__((ext_vector_type(8))) short s16x8;

#define B_    8
#define L_    8192
#define N_    256
#define DOUT_ 256

__device__ __forceinline__ unsigned short f2bf(float f) {
  unsigned int x = __float_as_uint(f);
  x += 0x7fff + ((x >> 16) & 1);   // RNE
  return (unsigned short)(x >> 16);
}

// ---------------- kernel 1: convert h, W to bf16 ----------------
__global__ void k_convert(const float* __restrict__ h, const float* __restrict__ W,
                          unsigned short* __restrict__ hb, unsigned short* __restrict__ Wb) {
  int t = blockIdx.x * 256 + threadIdx.x;
  int base = t * 4;
  const int TH = L_ * N_;      // 2097152
  const int TW = DOUT_ * N_;   // 65536
  if (base < TH) {
    float4 v = *(const float4*)(h + base);
    hb[base + 0] = f2bf(v.x); hb[base + 1] = f2bf(v.y);
    hb[base + 2] = f2bf(v.z); hb[base + 3] = f2bf(v.w);
  } else if (base < TH + TW) {
    int wb = base - TH;
    float4 v = *(const float4*)(W + wb);
    Wb[wb + 0] = f2bf(v.x); Wb[wb + 1] = f2bf(v.y);
    Wb[wb + 2] = f2bf(v.z); Wb[wb + 3] = f2bf(v.w);
  }
}

// ---- kernel 2: Amat[b][d][l'][i'] = (128d + l' - i' >= 0) ? u[b][128d+l'-i'] : 0 ----
// Block-Toeplitz chunks: main GEMM's A-tile (row-block r, k-chunk c) == Amat[b][r-c].
__global__ void k_amat(const float* __restrict__ u, unsigned short* __restrict__ Am) {
  int t = blockIdx.x * 256 + threadIdx.x;   // 8*64*128*16 = 1,048,576 threads
  int i0 = (t & 15) * 8;
  int lp = (t >> 4) & 127;
  int d  = (t >> 11) & 63;
  int b  = t >> 17;
  const float* ub = u + b * L_;
  int base = 128 * d + lp - i0;             // u index for j = 0
  s16x8 v;
#pragma unroll
  for (int j = 0; j < 8; ++j) {
    int idx = base - j;                     // max = 128*63+127 = 8191, never high-OOB
    float f = (idx >= 0) ? ub[idx] : 0.0f;  // upper triangle of d=0 block -> 0
    v[j] = (short)f2bf(f);
  }
  *(s16x8*)(Am + (size_t)t * 8) = v;        // 16B aligned store
}

// ---- kernel 3: gT[o][i] = sum_n W[o][n] * h[i][n]  (bf16 MFMA, fp32 acc) ----
// Direct-from-global MFMA: W rows are A (k-contiguous), h rows are B (k-contiguous).
__global__ void k_gt(const unsigned short* __restrict__ Wb, const unsigned short* __restrict__ hb,
                     unsigned short* __restrict__ gT) {
  int gid  = blockIdx.x * 256 + threadIdx.x;
  int lane = gid & 63;
  int wid  = gid >> 6;        // 0..2047
  int o_t  = wid >> 7;        // 0..15
  int i_t  = wid & 127;       // 0..127
  int o0 = o_t * 16, i0 = i_t * 64;
  int ln = lane & 15, hi = lane >> 4;
  f32x4 acc[4] = {};
#pragma unroll
  for (int k0 = 0; k0 < N_; k0 += 32) {
    s16x8 a = *(const s16x8*)(Wb + (o0 + ln) * N_ + k0 + 8 * hi);
#pragma unroll
    for (int ns = 0; ns < 4; ++ns) {
      s16x8 bfr = *(const s16x8*)(hb + (i0 + 16 * ns + ln) * N_ + k0 + 8 * hi);
      acc[ns] = __builtin_amdgcn_mfma_f32_16x16x32_bf16(a, bfr, acc[ns], 0, 0, 0);
    }
  }
  // C/D layout: row = 4*hi + q (o-dim), col = ln (i-dim)
#pragma unroll
  for (int ns = 0; ns < 4; ++ns)
#pragma unroll
    for (int q = 0; q < 4; ++q)
      gT[(size_t)(o0 + 4 * hi + q) * L_ + i0 + 16 * ns + ln] = f2bf(acc[ns][q]);
}

// ---------------- kernel 4: main Toeplitz GEMM ----------------
// out[b, 128r + l', ob + o'] = sum_i Amat-tiles @ gT-tiles, lower-triangular K-loop.
__global__ __launch_bounds__(256) void k_main(const unsigned short* __restrict__ Am,
                                              const unsigned short* __restrict__ gT,
                                              float* __restrict__ out) {
  __shared__ short Abuf[128 * 64];
  __shared__ short Bbuf[128 * 64];
  const int c = blockIdx.x;          // col-block (2)
  const int b = blockIdx.y;          // batch (8)
  const int r = 63 - blockIdx.z;     // row-block, heavy (long-K) first
  const int t = threadIdx.x;
  const int lane = t & 63;
  const int w = t >> 6;
  const int wm = (w >> 1) * 64, wn = (w & 1) * 64;   // 2x2 wave grid, 64x64 each
  const int ln = lane & 15, hi = lane >> 4;
  const int ob = c * 128;
  const int trow = t >> 3;           // 0..31
  const int tcol = (t & 7) * 8;      // element col within 64-wide tile
  f32x4 acc[4][4] = {};

  const int nkt = 2 * (r + 1);       // K covers i in [0, 128*(r+1))
  for (int kt = 0; kt < nkt; ++kt) {
    const int i0   = kt * 64;
    const int d    = r - (kt >> 1);
    const int ioff = (kt & 1) * 64;
    const unsigned short* Asrc = Am + (((size_t)(b * 64 + d)) << 14) + ioff + tcol;
    const unsigned short* Bsrc = gT + (size_t)(ob + trow) * L_ + i0 + tcol;
#pragma unroll
    for (int call = 0; call < 4; ++call) {
      __builtin_amdgcn_global_load_lds(
          (const __attribute__((address_space(1))) void*)(Asrc + (size_t)(call * 32 + trow) * 128),
          (__attribute__((address_space(3))) void*)(Abuf + call * 2048 + t * 8),
          16, 0, 0);
    }
#pragma unroll
    for (int call = 0; call < 4; ++call) {
      __builtin_amdgcn_global_load_lds(
          (const __attribute__((address_space(1))) void*)(Bsrc + (size_t)(call * 32) * L_),
          (__attribute__((address_space(3))) void*)(Bbuf + call * 2048 + t * 8),
          16, 0, 0);
    }
    __syncthreads();   // compiler drains vmcnt before s_barrier
#pragma unroll
    for (int k0 = 0; k0 < 64; k0 += 32) {
      s16x8 af[4], bfr[4];
#pragma unroll
      for (int m = 0; m < 4; ++m)
        af[m] = *(const s16x8*)(Abuf + (wm + m * 16 + ln) * 64 + k0 + 8 * hi);
#pragma unroll
      for (int n = 0; n < 4; ++n)
        bfr[n] = *(const s16x8*)(Bbuf + (wn + n * 16 + ln) * 64 + k0 + 8 * hi);
#pragma unroll
      for (int m = 0; m < 4; ++m)
#pragma unroll
        for (int n = 0; n < 4; ++n)
          acc[m][n] = __builtin_amdgcn_mfma_f32_16x16x32_bf16(af[m], bfr[n], acc[m][n], 0, 0, 0);
    }
    __syncthreads();
  }

  // epilogue: D row = l-dim (4*hi + q), col = o-dim (ln)
  const int lb = r * 128;
#pragma unroll
  for (int m = 0; m < 4; ++m)
#pragma unroll
    for (int n = 0; n < 4; ++n)
#pragma unroll
      for (int q = 0; q < 4; ++q) {
        int l = lb + wm + m * 16 + 4 * hi + q;
        int o = ob + wn + n * 16 + ln;
        out[(size_t)(b * L_ + l) * DOUT_ + o] = acc[m][n][q];
      }
}

extern "C" void kernel_launch(void* const* d_in, const int* in_sizes, int n_in,
                              void* d_out, int out_size, void* d_ws, size_t ws_size,
                              hipStream_t stream) {
  const float* u = (const float*)d_in[0];   // [8, 8192, 1]
  const float* h = (const float*)d_in[1];   // [8192, 256]
  const float* W = (const float*)d_in[2];   // [256, 256]
  float* out = (float*)d_out;               // [8, 8192, 256]

  char* ws = (char*)d_ws;
  unsigned short* hb = (unsigned short*)(ws);                                   // 4 MB
  unsigned short* Wb = (unsigned short*)(ws + (size_t)4 * 1024 * 1024);         // 128 KB
  unsigned short* gT = (unsigned short*)(ws + (size_t)4 * 1024 * 1024 + 131072);// 4 MB
  unsigned short* Am = (unsigned short*)(ws + (size_t)8 * 1024 * 1024 + 131072);// 16 MB

  k_convert<<<2112, 256, 0, stream>>>(h, W, hb, Wb);
  k_amat<<<4096, 256, 0, stream>>>(u, Am);
  k_gt<<<512, 256, 0, stream>>>(Wb, hb, gT);
  k_main<<<dim3(2, 8, 64), 256, 0, stream>>>(Am, gT, out);
}

// Round 2
// 200.989 us; speedup vs baseline: 1.0967x; 1.0967x over previous
//
#include <hip/hip_runtime.h>
#include <hip/hip_bf16.h>
#include <stdint.h>
#include <stddef.h>

typedef __attribute__((ext_vector_type(4))) float f32x4;
typedef __attribute__((ext_vector_type(8))) short s16x8;

#define B_    8
#define L_    8192
#define N_    256
#define DOUT_ 256

__device__ __forceinline__ unsigned short f2bf(float f) {
  unsigned int x = __float_as_uint(f);
  x += 0x7fff + ((x >> 16) & 1);   // RNE
  return (unsigned short)(x >> 16);
}

// ---------------- kernel 1: convert h, W to bf16 ----------------
__global__ void k_convert(const float* __restrict__ h, const float* __restrict__ W,
                          unsigned short* __restrict__ hb, unsigned short* __restrict__ Wb) {
  int t = blockIdx.x * 256 + threadIdx.x;
  int base = t * 4;
  const int TH = L_ * N_;      // 2097152
  const int TW = DOUT_ * N_;   // 65536
  if (base < TH) {
    float4 v = *(const float4*)(h + base);
    hb[base + 0] = f2bf(v.x); hb[base + 1] = f2bf(v.y);
    hb[base + 2] = f2bf(v.z); hb[base + 3] = f2bf(v.w);
  } else if (base < TH + TW) {
    int wb = base - TH;
    float4 v = *(const float4*)(W + wb);
    Wb[wb + 0] = f2bf(v.x); Wb[wb + 1] = f2bf(v.y);
    Wb[wb + 2] = f2bf(v.z); Wb[wb + 3] = f2bf(v.w);
  }
}

// ---- kernel 2: Amat[b][d][l'][i'] (65 d-slots; slot 64 = zeros for above-diagonal) ----
__global__ void k_amat(const float* __restrict__ u, unsigned short* __restrict__ Am) {
  int t = blockIdx.x * 256 + threadIdx.x;   // 4160 blocks * 256 = 8*65*128*16 threads
  int i0 = (t & 15) * 8;
  int lp = (t >> 4) & 127;
  int r2 = t >> 11;           // b*65 + d
  int d  = r2 % 65;
  int b  = r2 / 65;
  s16x8 v;
#pragma unroll
  for (int j = 0; j < 8; ++j) v[j] = 0;
  if (d < 64) {
    const float* ub = u + b * L_;
    int base = 128 * d + lp - i0;
#pragma unroll
    for (int j = 0; j < 8; ++j) {
      int idx = base - j;                     // max 8191, never high-OOB
      float f = (idx >= 0) ? ub[idx] : 0.0f;
      v[j] = (short)f2bf(f);
    }
  }
  *(s16x8*)(Am + (size_t)t * 8) = v;
}

// ---- kernel 3: gT[o][i] = sum_n W[o][n] * h[i][n]  (bf16 MFMA, fp32 acc) ----
__global__ void k_gt(const unsigned short* __restrict__ Wb, const unsigned short* __restrict__ hb,
                     unsigned short* __restrict__ gT) {
  int gid  = blockIdx.x * 256 + threadIdx.x;
  int lane = gid & 63;
  int wid  = gid >> 6;        // 0..2047
  int o_t  = wid >> 7;        // 0..15
  int i_t  = wid & 127;       // 0..127
  int o0 = o_t * 16, i0 = i_t * 64;
  int ln = lane & 15, hi = lane >> 4;
  f32x4 acc[4] = {};
#pragma unroll
  for (int k0 = 0; k0 < N_; k0 += 32) {
    s16x8 a = *(const s16x8*)(Wb + (o0 + ln) * N_ + k0 + 8 * hi);
#pragma unroll
    for (int ns = 0; ns < 4; ++ns) {
      s16x8 bfr = *(const s16x8*)(hb + (i0 + 16 * ns + ln) * N_ + k0 + 8 * hi);
      acc[ns] = __builtin_amdgcn_mfma_f32_16x16x32_bf16(a, bfr, acc[ns], 0, 0, 0);
    }
  }
#pragma unroll
  for (int ns = 0; ns < 4; ++ns)
#pragma unroll
    for (int q = 0; q < 4; ++q)
      gT[(size_t)(o0 + 4 * hi + q) * L_ + i0 + 16 * ns + ln] = f2bf(acc[ns][q]);
}

// ---------------- kernel 4: main Toeplitz GEMM, pipelined + swizzled ----------------
// BM=256 BN=128 BK=64, 8 waves (4Mx2N, 64x64 each). 2-deep LDS dbuf, counted vmcnt(4),
// XOR slot-swizzle (slot ^= row&7) on both stage-source and ds_read.
__global__ __launch_bounds__(512, 2) void k_main(const unsigned short* __restrict__ Am,
                                                 const unsigned short* __restrict__ gT,
                                                 float* __restrict__ out) {
  __shared__ short As[2][16384];   // [buf][256 rows][64 k] swizzled, 64 KB
  __shared__ short Bs[2][8192];    // [buf][128 rows][64 k] swizzled, 32 KB
  const int c = blockIdx.x;          // col-block (2)
  const int b = blockIdx.y;          // batch (8)
  const int R = 31 - blockIdx.z;     // 256-row block, heavy (long-K) first
  const int tid = threadIdx.x;
  const int lane = tid & 63;
  const int w = tid >> 6;
  const int wr = w >> 1, wc = w & 1;
  const int ln = lane & 15, hi = lane >> 4;
  const int ob = c * 128;

  // ---- staging precompute: thread tid owns chunk (row = tid>>3 + 64q, phys slot = tid&7) ----
  const int t3 = tid >> 3;
  const int sA = ((tid & 7) ^ (t3 & 7)) << 3;    // logical slot offset (shorts), XOR-swizzled
  const unsigned short* AmB = Am + (size_t)(b * 65) * 16384;
  const unsigned short* Bb0 = gT + (size_t)(ob + t3) * L_ + sA;
  const unsigned short* Bb1 = gT + (size_t)(ob + t3 + 64) * L_ + sA;
  const int rl0 = t3;        // rowlow for q even
  const int rl1 = 64 + t3;   // rowlow for q odd

  // ---- fragment-read precompute (swizzled ds_read addresses, shorts) ----
  const int offA = (wr * 64 + ln) * 64;
  const int offB = (wc * 64 + ln) * 64;
  const int sw = ln & 7;
  const int off_k0 = (hi ^ sw) * 8;
  const int off_k1 = ((hi + 4) ^ sw) * 8;

  f32x4 acc[4][4] = {};
  const int nkt = 4 * (R + 1);

#define ISSUE_A(ktv, buf) do { \
    const int kthalf_ = (ktv) >> 1; const int kodd_ = ((ktv) & 1) << 6; \
    _Pragma("unroll") \
    for (int q = 0; q < 4; ++q) { \
      int dd = 2 * R + (q >> 1) - kthalf_; \
      int sd = dd < 0 ? 64 : dd; \
      const unsigned short* src = AmB + ((size_t)sd << 14) + ((q & 1 ? rl1 : rl0) << 7) + kodd_ + sA; \
      __builtin_amdgcn_global_load_lds((const __attribute__((address_space(1))) void*)src, \
          (__attribute__((address_space(3))) void*)(&As[buf][(tid + 512 * q) * 8]), 16, 0, 0); \
    } \
  } while (0)

#define ISSUE_B(ktv, buf) do { \
    const int kb_ = (ktv) * 64; \
    __builtin_amdgcn_global_load_lds((const __attribute__((address_space(1))) void*)(Bb0 + kb_), \
        (__attribute__((address_space(3))) void*)(&Bs[buf][tid * 8]), 16, 0, 0); \
    __builtin_amdgcn_global_load_lds((const __attribute__((address_space(1))) void*)(Bb1 + kb_), \
        (__attribute__((address_space(3))) void*)(&Bs[buf][(tid + 512) * 8]), 16, 0, 0); \
  } while (0)

  ISSUE_A(0, 0);
  ISSUE_B(0, 0);

  for (int kt = 0; kt < nkt; ++kt) {
    const int cur = kt & 1;
    const int nxt = cur ^ 1;
    const int kt1 = (kt + 1 < nkt) ? kt + 1 : kt;   // clamp keeps vmcnt count exact

    // ---- P0: prefetch next A (4 loads), wait tile-kt's 6 oldest, MFMA fn-half 0 ----
    ISSUE_A(kt1, nxt);
    asm volatile("s_waitcnt vmcnt(4)" ::: "memory");
    __builtin_amdgcn_sched_barrier(0);
    __builtin_amdgcn_s_barrier();
    __builtin_amdgcn_sched_barrier(0);
    const short* Ac = &As[cur][0];
    const short* Bc = &Bs[cur][0];
    s16x8 af[4][2], bf[2][2];
#pragma unroll
    for (int m = 0; m < 4; ++m) {
      af[m][0] = *(const s16x8*)(Ac + offA + m * 1024 + off_k0);
      af[m][1] = *(const s16x8*)(Ac + offA + m * 1024 + off_k1);
    }
#pragma unroll
    for (int n = 0; n < 2; ++n) {
      bf[n][0] = *(const s16x8*)(Bc + offB + n * 1024 + off_k0);
      bf[n][1] = *(const s16x8*)(Bc + offB + n * 1024 + off_k1);
    }
    __builtin_amdgcn_s_setprio(1);
#pragma unroll
    for (int kk = 0; kk < 2; ++kk)
#pragma unroll
      for (int m = 0; m < 4; ++m)
#pragma unroll
        for (int n = 0; n < 2; ++n)
          acc[m][n] = __builtin_amdgcn_mfma_f32_16x16x32_bf16(af[m][kk], bf[n][kk], acc[m][n], 0, 0, 0);
    __builtin_amdgcn_s_setprio(0);

    // ---- P1: prefetch next B (2 loads), MFMA fn-half 1 ----
    ISSUE_B(kt1, nxt);
    s16x8 bg[2][2];
#pragma unroll
    for (int n = 0; n < 2; ++n) {
      bg[n][0] = *(const s16x8*)(Bc + offB + (n + 2) * 1024 + off_k0);
      bg[n][1] = *(const s16x8*)(Bc + offB + (n + 2) * 1024 + off_k1);
    }
    __builtin_amdgcn_s_setprio(1);
#pragma unroll
    for (int kk = 0; kk < 2; ++kk)
#pragma unroll
      for (int m = 0; m < 4; ++m)
#pragma unroll
        for (int n = 0; n < 2; ++n)
          acc[m][n + 2] = __builtin_amdgcn_mfma_f32_16x16x32_bf16(af[m][kk], bg[n][kk], acc[m][n + 2], 0, 0, 0);
    __builtin_amdgcn_s_setprio(0);
    __builtin_amdgcn_sched_barrier(0);
    __builtin_amdgcn_s_barrier();
    __builtin_amdgcn_sched_barrier(0);
  }

  // drain in-flight LDS writes before workgroup teardown (next block reuses this LDS)
  asm volatile("s_waitcnt vmcnt(0)" ::: "memory");

  // ---- epilogue: D row = l (4*hi+q), col = o (ln) ----
  const int l0 = R * 256 + wr * 64 + 4 * hi;
  const int o0 = ob + wc * 64 + ln;
  float* outb = out + (size_t)b * L_ * DOUT_;
#pragma unroll
  for (int m = 0; m < 4; ++m)
#pragma unroll
    for (int q = 0; q < 4; ++q) {
      float* rowp = outb + (size_t)(l0 + m * 16 + q) * DOUT_ + o0;
#pragma unroll
      for (int n = 0; n < 4; ++n)
        rowp[n * 16] = acc[m][n][q];
    }
#undef ISSUE_A
#undef ISSUE_B
}

extern "C" void kernel_launch(void* const* d_in, const int* in_sizes, int n_in,
                              void* d_out, int out_size, void* d_ws, size_t ws_size,
                              hipStream_t stream) {
  const float* u = (const float*)d_in[0];   // [8, 8192, 1]
  const float* h = (const float*)d_in[1];   // [8192, 256]
  const float* W = (const float*)d_in[2];   // [256, 256]
  float* out = (float*)d_out;               // [8, 8192, 256]

  char* ws = (char*)d_ws;
  const size_t AM_BYTES = (size_t)8 * 65 * 16384 * 2;              // 17,039,360
  unsigned short* Am = (unsigned short*)ws;                        // overlays hb (hb dead by then)
  unsigned short* gT = (unsigned short*)(ws + AM_BYTES);           // 4 MB
  unsigned short* Wb = (unsigned short*)(ws + AM_BYTES + (size_t)4 * 1024 * 1024); // 128 KB
  unsigned short* hb = (unsigned short*)ws;                        // temp, consumed by k_gt

  k_convert<<<2112, 256, 0, stream>>>(h, W, hb, Wb);
  k_gt<<<512, 256, 0, stream>>>(Wb, hb, gT);        // uses hb, then hb is dead
  k_amat<<<4160, 256, 0, stream>>>(u, Am);          // overwrites hb region
  k_main<<<dim3(2, 8, 32), 512, 0, stream>>>(Am, gT, out);
}

// Round 3
// 176.667 us; speedup vs baseline: 1.2477x; 1.1377x over previous
//
#include <hip/hip_runtime.h>
#include <hip/hip_bf16.h>
#include <stdint.h>
#include <stddef.h>

typedef __attribute__((ext_vector_type(4))) float f32x4;
typedef __attribute__((ext_vector_type(8))) short s16x8;

#define B_    8
#define L_    8192
#define N_    256
#define DOUT_ 256

__device__ __forceinline__ unsigned short f2bf(float f) {
  unsigned int x = __float_as_uint(f);
  x += 0x7fff + ((x >> 16) & 1);   // RNE
  return (unsigned short)(x >> 16);
}

// ---- kernel 1: Amat[b][d][l'][i'] (65 d-slots; slot 64 = zeros for above-diagonal) ----
__global__ void k_amat(const float* __restrict__ u, unsigned short* __restrict__ Am) {
  int t = blockIdx.x * 256 + threadIdx.x;   // 4160 blocks * 256 = 8*65*128*16 threads
  int i0 = (t & 15) * 8;
  int lp = (t >> 4) & 127;
  int r2 = t >> 11;           // b*65 + d
  int d  = r2 % 65;
  int b  = r2 / 65;
  s16x8 v;
#pragma unroll
  for (int j = 0; j < 8; ++j) v[j] = 0;
  if (d < 64) {
    const float* ub = u + b * L_;
    int base = 128 * d + lp - i0;
#pragma unroll
    for (int j = 0; j < 8; ++j) {
      int idx = base - j;                     // max 8191, never high-OOB
      float f = (idx >= 0) ? ub[idx] : 0.0f;
      v[j] = (short)f2bf(f);
    }
  }
  *(s16x8*)(Am + (size_t)t * 8) = v;
}

// ---- kernel 2: gT[o][i] = sum_n W[o][n] * h[i][n], inline f32->bf16 convert ----
__global__ void k_gt(const float* __restrict__ W, const float* __restrict__ h,
                     unsigned short* __restrict__ gT) {
  int gid  = blockIdx.x * 256 + threadIdx.x;
  int lane = gid & 63;
  int wid  = gid >> 6;        // 0..2047
  int o_t  = wid >> 7;        // 0..15
  int i_t  = wid & 127;       // 0..127
  int o0 = o_t * 16, i0 = i_t * 64;
  int ln = lane & 15, hi = lane >> 4;
  f32x4 acc[4] = {};
#pragma unroll
  for (int k0 = 0; k0 < N_; k0 += 32) {
    const float* wp = W + (o0 + ln) * N_ + k0 + 8 * hi;
    float4 w0 = *(const float4*)wp;
    float4 w1 = *(const float4*)(wp + 4);
    s16x8 a;
    a[0] = (short)f2bf(w0.x); a[1] = (short)f2bf(w0.y);
    a[2] = (short)f2bf(w0.z); a[3] = (short)f2bf(w0.w);
    a[4] = (short)f2bf(w1.x); a[5] = (short)f2bf(w1.y);
    a[6] = (short)f2bf(w1.z); a[7] = (short)f2bf(w1.w);
#pragma unroll
    for (int ns = 0; ns < 4; ++ns) {
      const float* hp = h + (size_t)(i0 + 16 * ns + ln) * N_ + k0 + 8 * hi;
      float4 h0 = *(const float4*)hp;
      float4 h1 = *(const float4*)(hp + 4);
      s16x8 bb;
      bb[0] = (short)f2bf(h0.x); bb[1] = (short)f2bf(h0.y);
      bb[2] = (short)f2bf(h0.z); bb[3] = (short)f2bf(h0.w);
      bb[4] = (short)f2bf(h1.x); bb[5] = (short)f2bf(h1.y);
      bb[6] = (short)f2bf(h1.z); bb[7] = (short)f2bf(h1.w);
      acc[ns] = __builtin_amdgcn_mfma_f32_16x16x32_bf16(a, bb, acc[ns], 0, 0, 0);
    }
  }
#pragma unroll
  for (int ns = 0; ns < 4; ++ns)
#pragma unroll
    for (int q = 0; q < 4; ++q)
      gT[(size_t)(o0 + 4 * hi + q) * L_ + i0 + 16 * ns + ln] = f2bf(acc[ns][q]);
}

// ---------------- kernel 3: main Toeplitz GEMM ----------------
// BM=256 BN=128 BK=64, 8 waves (4Mx2N), 3-deep LDS pipeline, vmcnt(6), one barrier/K-step,
// XOR slot-swizzle both sides. Each block does row-blocks R=31-z and R=z (132 K-steps, equal).
__global__ __launch_bounds__(512, 2) void k_main(const unsigned short* __restrict__ Am,
                                                 const unsigned short* __restrict__ gT,
                                                 float* __restrict__ out) {
  __shared__ short As[3][16384];   // 96 KB
  __shared__ short Bs[3][8192];    // 48 KB  (total 144 KB)
  const int c = blockIdx.x;          // col-block (2)
  const int b = blockIdx.y;          // batch (8)
  const int z = blockIdx.z;          // 0..15
  const int tid = threadIdx.x;
  const int lane = tid & 63;
  const int w = tid >> 6;
  const int wr = w >> 1, wc = w & 1;
  const int ln = lane & 15, hi = lane >> 4;
  const int ob = c * 128;

  // staging precompute: thread owns chunk (row = tid>>3 (+64q), phys slot = tid&7)
  const int t3 = tid >> 3;
  const int sA = ((tid & 7) ^ (t3 & 7)) << 3;    // XOR-swizzled logical slot (shorts)
  const unsigned short* AmB = Am + (size_t)(b * 65) * 16384;
  const unsigned short* Bb0 = gT + (size_t)(ob + t3) * L_ + sA;
  const unsigned short* Bb1 = gT + (size_t)(ob + t3 + 64) * L_ + sA;
  const int rl0 = t3;
  const int rl1 = 64 + t3;

  // fragment-read precompute (swizzled ds_read addresses, shorts)
  const int offA = (wr * 64 + ln) * 64;
  const int offB = (wc * 64 + ln) * 64;
  const int sw = ln & 7;
  const int off_k0 = (hi ^ sw) * 8;
  const int off_k1 = ((hi + 4) ^ sw) * 8;

  float* outb = out + (size_t)b * L_ * DOUT_;

#define ISSUE_A(Rv, ktv, dst) do { \
    const int kthalf_ = (ktv) >> 1; const int kodd_ = ((ktv) & 1) << 6; \
    _Pragma("unroll") \
    for (int q = 0; q < 4; ++q) { \
      int dd = 2 * (Rv) + (q >> 1) - kthalf_; \
      int sd = dd < 0 ? 64 : dd; \
      const unsigned short* src = AmB + ((size_t)sd << 14) + ((q & 1 ? rl1 : rl0) << 7) + kodd_ + sA; \
      __builtin_amdgcn_global_load_lds((const __attribute__((address_space(1))) void*)src, \
          (__attribute__((address_space(3))) void*)((dst) + (tid + 512 * q) * 8), 16, 0, 0); \
    } \
  } while (0)

#define ISSUE_B(ktv, dst) do { \
    const int kb_ = (ktv) * 64; \
    __builtin_amdgcn_global_load_lds((const __attribute__((address_space(1))) void*)(Bb0 + kb_), \
        (__attribute__((address_space(3))) void*)((dst) + tid * 8), 16, 0, 0); \
    __builtin_amdgcn_global_load_lds((const __attribute__((address_space(1))) void*)(Bb1 + kb_), \
        (__attribute__((address_space(3))) void*)((dst) + (tid + 512) * 8), 16, 0, 0); \
  } while (0)

  auto run_section = [&](const int R) {
    short *ar = &As[0][0], *an = &As[1][0], *aw = &As[2][0];
    short *br = &Bs[0][0], *bn = &Bs[1][0], *bw = &Bs[2][0];
    f32x4 acc[4][4] = {};
    const int nkt = 4 * (R + 1);

    // prologue: tiles 0,1  (caller guarantees vmcnt==0 and LDS free here)
    ISSUE_A(R, 0, ar); ISSUE_B(0, br);
    ISSUE_A(R, 1, an); ISSUE_B(1, bn);

    for (int kt = 0; kt < nkt; ++kt) {
      // entry: own tile-kt loads landed (6 newest = tile kt+1), then all waves' visible
      asm volatile("s_waitcnt vmcnt(6)" ::: "memory");
      __builtin_amdgcn_sched_barrier(0);
      __builtin_amdgcn_s_barrier();
      __builtin_amdgcn_sched_barrier(0);

      const int kt2 = (kt + 2 < nkt) ? kt + 2 : nkt - 1;   // clamp keeps 6 issues/iter

      s16x8 af[4][2], bf[2][2];
#pragma unroll
      for (int m = 0; m < 4; ++m) {
        af[m][0] = *(const s16x8*)(ar + offA + m * 1024 + off_k0);
        af[m][1] = *(const s16x8*)(ar + offA + m * 1024 + off_k1);
      }
#pragma unroll
      for (int n = 0; n < 2; ++n) {
        bf[n][0] = *(const s16x8*)(br + offB + n * 1024 + off_k0);
        bf[n][1] = *(const s16x8*)(br + offB + n * 1024 + off_k1);
      }
      ISSUE_A(R, kt2, aw);                 // prefetch 2 tiles ahead (A half)
      __builtin_amdgcn_s_setprio(1);
#pragma unroll
      for (int kk = 0; kk < 2; ++kk)
#pragma unroll
        for (int m = 0; m < 4; ++m)
#pragma unroll
          for (int n = 0; n < 2; ++n)
            acc[m][n] = __builtin_amdgcn_mfma_f32_16x16x32_bf16(af[m][kk], bf[n][kk], acc[m][n], 0, 0, 0);
      __builtin_amdgcn_s_setprio(0);

      s16x8 bg[2][2];
#pragma unroll
      for (int n = 0; n < 2; ++n) {
        bg[n][0] = *(const s16x8*)(br + offB + (n + 2) * 1024 + off_k0);
        bg[n][1] = *(const s16x8*)(br + offB + (n + 2) * 1024 + off_k1);
      }
      ISSUE_B(kt2, bw);                    // prefetch 2 tiles ahead (B half)
      __builtin_amdgcn_s_setprio(1);
#pragma unroll
      for (int kk = 0; kk < 2; ++kk)
#pragma unroll
        for (int m = 0; m < 4; ++m)
#pragma unroll
          for (int n = 0; n < 2; ++n)
            acc[m][n + 2] = __builtin_amdgcn_mfma_f32_16x16x32_bf16(af[m][kk], bg[n][kk], acc[m][n + 2], 0, 0, 0);
      __builtin_amdgcn_s_setprio(0);

      short* t;
      t = ar; ar = an; an = aw; aw = t;
      t = br; br = bn; bn = bw; bw = t;
    }

    // all waves done reading; drain in-flight (dummy) LDS writes before reuse
    __builtin_amdgcn_s_barrier();
    asm volatile("s_waitcnt vmcnt(0)" ::: "memory");

    // epilogue: D row = l (4*hi+q), col = o (ln)
    const int l0 = R * 256 + wr * 64 + 4 * hi;
    const int o0 = ob + wc * 64 + ln;
#pragma unroll
    for (int m = 0; m < 4; ++m)
#pragma unroll
      for (int q = 0; q < 4; ++q) {
        float* rowp = outb + (size_t)(l0 + m * 16 + q) * DOUT_ + o0;
#pragma unroll
        for (int n = 0; n < 4; ++n)
          rowp[n * 16] = acc[m][n][q];
      }
  };

  run_section(31 - z);   // heavy row-block
  run_section(z);        // light row-block: total K-steps = 132 for every block

#undef ISSUE_A
#undef ISSUE_B
}

extern "C" void kernel_launch(void* const* d_in, const int* in_sizes, int n_in,
                              void* d_out, int out_size, void* d_ws, size_t ws_size,
                              hipStream_t stream) {
  const float* u = (const float*)d_in[0];   // [8, 8192, 1]
  const float* h = (const float*)d_in[1];   // [8192, 256]
  const float* W = (const float*)d_in[2];   // [256, 256]
  float* out = (float*)d_out;               // [8, 8192, 256]

  char* ws = (char*)d_ws;
  const size_t AM_BYTES = (size_t)8 * 65 * 16384 * 2;     // 17,039,360
  unsigned short* Am = (unsigned short*)ws;
  unsigned short* gT = (unsigned short*)(ws + AM_BYTES);  // 4 MB

  k_amat<<<4160, 256, 0, stream>>>(u, Am);
  k_gt<<<512, 256, 0, stream>>>(W, h, gT);
  k_main<<<dim3(2, 8, 16), 512, 0, stream>>>(Am, gT, out);
}